// Round 3
// baseline (1047.704 us; speedup 1.0000x reference)
//
#include <hip/hip_runtime.h>

#define B2 2
#define NQ 2048
#define NK 2048
#define DM 1024
#define NH 16
#define DK 64

typedef unsigned short u16;
typedef __attribute__((ext_vector_type(8))) short bf16x8;
typedef __attribute__((ext_vector_type(4))) float f32x4;

__device__ __forceinline__ u16 f2bf(float f) {
  unsigned u = __float_as_uint(f);
  u += 0x7FFFu + ((u >> 16) & 1u);
  return (u16)(u >> 16);
}

#if __has_builtin(__builtin_amdgcn_exp2f)
#define EXP2F(x) __builtin_amdgcn_exp2f(x)
#else
#define EXP2F(x) exp2f(x)
#endif

#define MFMA(a, b, c) __builtin_amdgcn_mfma_f32_16x16x32_bf16(a, b, c, 0, 0, 0)

// exp(x*wgt/8) = exp2(x*wgt*log2(e)/8)
#define EXPC 0.18033688011112043f

// ---------------- K0: fp32 -> bf16 convert (3 x 4M activations, 4 x 1M weights) ---------
__global__ __launch_bounds__(256) void k_convert(
    const float* __restrict__ s0, const float* __restrict__ s1, const float* __restrict__ s2,
    const float* __restrict__ s3, const float* __restrict__ s4, const float* __restrict__ s5,
    const float* __restrict__ s6,
    u16* __restrict__ d0, u16* __restrict__ d1, u16* __restrict__ d2, u16* __restrict__ d3,
    u16* __restrict__ d4, u16* __restrict__ d5, u16* __restrict__ d6) {
  const int j = blockIdx.y;
  const int n = (j < 3) ? (4 * 1024 * 1024) : (1024 * 1024);
  const int i = (blockIdx.x * 256 + threadIdx.x) * 4;
  if (i >= n) return;
  const float* s = (j == 0) ? s0 : (j == 1) ? s1 : (j == 2) ? s2 : (j == 3) ? s3
                  : (j == 4) ? s4 : (j == 5) ? s5 : s6;
  u16* d = (j == 0) ? d0 : (j == 1) ? d1 : (j == 2) ? d2 : (j == 3) ? d3
          : (j == 4) ? d4 : (j == 5) ? d5 : d6;
  const float4 f = *(const float4*)(s + i);
  ushort4 o;
  o.x = f2bf(f.x); o.y = f2bf(f.y); o.z = f2bf(f.z); o.w = f2bf(f.w);
  *(ushort4*)(d + i) = o;
}

// ---------------- shared 128x128 bf16 GEMM core: Y = A[M,1024] * W[N,1024]^T -----------
// 256 threads = 4 waves (2x2), each wave 64x64 (4x4 frags of 16x16x32).
__device__ __forceinline__ void gemm_core(
    const u16* __restrict__ A, const u16* __restrict__ Wm,
    int tm, int tn, u16* As, u16* Bs, f32x4 acc[4][4]) {
  const int tid = threadIdx.x;
  const int lane = tid & 63;
  const int wid = tid >> 6;
  const int wm = (wid >> 1) * 64, wn = (wid & 1) * 64;
  const int cc = lane & 15, gg = lane >> 4;
  const int srow = tid >> 2, scol = 8 * (tid & 3);
  const size_t ra0 = (size_t)(tm + srow) * DM + scol;
  const size_t ra1 = (size_t)(tm + 64 + srow) * DM + scol;
  const size_t rb0 = (size_t)(tn + srow) * DM + scol;
  const size_t rb1 = (size_t)(tn + 64 + srow) * DM + scol;
  const f32x4 Z4 = {0.f, 0.f, 0.f, 0.f};
#pragma unroll
  for (int i = 0; i < 4; i++)
#pragma unroll
    for (int j = 0; j < 4; j++) acc[i][j] = Z4;

  // prologue stage (buf 0, kk = 0)
  *(bf16x8*)&As[tid * 8]        = *(const bf16x8*)(A + ra0);
  *(bf16x8*)&As[2048 + tid * 8] = *(const bf16x8*)(A + ra1);
  *(bf16x8*)&Bs[tid * 8]        = *(const bf16x8*)(Wm + rb0);
  *(bf16x8*)&Bs[2048 + tid * 8] = *(const bf16x8*)(Wm + rb1);

  int buf = 0;
  for (int kk = 0; kk < DM; kk += 32) {
    __syncthreads();
    const int o = buf * 4096;
    bf16x8 af[4], bv[4];
#pragma unroll
    for (int i = 0; i < 4; i++) af[i] = *(const bf16x8*)&As[o + (wm + i * 16 + cc) * 32 + 8 * gg];
#pragma unroll
    for (int i = 0; i < 4; i++) bv[i] = *(const bf16x8*)&Bs[o + (wn + i * 16 + cc) * 32 + 8 * gg];
    if (kk + 32 < DM) {  // stage next K-slice into other buffer (overlaps MFMA)
      const int p = (buf ^ 1) * 4096;
      *(bf16x8*)&As[p + tid * 8]        = *(const bf16x8*)(A + ra0 + kk + 32);
      *(bf16x8*)&As[p + 2048 + tid * 8] = *(const bf16x8*)(A + ra1 + kk + 32);
      *(bf16x8*)&Bs[p + tid * 8]        = *(const bf16x8*)(Wm + rb0 + kk + 32);
      *(bf16x8*)&Bs[p + 2048 + tid * 8] = *(const bf16x8*)(Wm + rb1 + kk + 32);
    }
#pragma unroll
    for (int mi = 0; mi < 4; mi++)
#pragma unroll
      for (int ni = 0; ni < 4; ni++) acc[mi][ni] = MFMA(af[mi], bv[ni], acc[mi][ni]);
    buf ^= 1;
  }
}

// ---------------- K1: QKV projections (z = 0/1/2 -> q/k/v), masked, head-split bf16 ----
__global__ __launch_bounds__(256) void k_proj(
    const u16* __restrict__ xq, const u16* __restrict__ xk, const u16* __restrict__ xv,
    const u16* __restrict__ wqb, const u16* __restrict__ wkb, const u16* __restrict__ wvb,
    const float* __restrict__ bq, const float* __restrict__ bk, const float* __restrict__ bv,
    const float* __restrict__ qmask, const float* __restrict__ kmask,
    u16* __restrict__ q_ws, u16* __restrict__ k_ws, u16* __restrict__ vT_ws) {
  __shared__ u16 As[2 * 4096];
  __shared__ u16 Bs[2 * 4096];
  const int z = blockIdx.z;
  const u16* A = (z == 0) ? xq : (z == 1) ? xk : xv;
  const u16* Wm = (z == 0) ? wqb : (z == 1) ? wkb : wvb;
  const float* bias = (z == 0) ? bq : (z == 1) ? bk : bv;
  const float* rmask = (z == 0) ? qmask : kmask;
  const int tm = blockIdx.x * 128, tn = blockIdx.y * 128;
  f32x4 acc[4][4];
  gemm_core(A, Wm, tm, tn, As, Bs, acc);

  const int lane = threadIdx.x & 63;
  const int wid = threadIdx.x >> 6;
  const int wm = (wid >> 1) * 64, wn = (wid & 1) * 64;
  const int cc = lane & 15, gg = lane >> 4;
  const int b = tm >> 11;
  const int tok0 = tm & 2047;
#pragma unroll
  for (int mi = 0; mi < 4; mi++) {
    const int rl = wm + mi * 16 + 4 * gg;  // row in tile (token offset)
    float rm[4];
#pragma unroll
    for (int r = 0; r < 4; r++) rm[r] = rmask[b * NQ + tok0 + rl + r];
#pragma unroll
    for (int ni = 0; ni < 4; ni++) {
      const int col = tn + wn + ni * 16 + cc;
      const int h = col >> 6, d = col & 63;
      const float bs = bias[col];
      f32x4 a = acc[mi][ni];
      if (z <= 1) {
        u16* dst = ((z == 0) ? q_ws : k_ws) +
                   ((size_t)(b * NH + h) * NQ + tok0 + rl) * DK + d;
#pragma unroll
        for (int r = 0; r < 4; r++) dst[(size_t)r * DK] = f2bf((a[r] + bs) * rm[r]);
      } else {
        ushort4 pk;
        pk.x = f2bf((a[0] + bs) * rm[0]);
        pk.y = f2bf((a[1] + bs) * rm[1]);
        pk.z = f2bf((a[2] + bs) * rm[2]);
        pk.w = f2bf((a[3] + bs) * rm[3]);
        *(ushort4*)(vT_ws + ((size_t)(b * NH + h) * DK + d) * NK + tok0 + rl) = pk;
      }
    }
  }
}

// ---------------- K2: softmax denominators l[b,h,q] = sum_k exp(logit) ----------------
__global__ __launch_bounds__(256) void k_stats(
    const u16* __restrict__ q_ws, const u16* __restrict__ k_ws,
    const float* __restrict__ attw, const int* __restrict__ amask,
    float* __restrict__ l_ws) {
  __shared__ u16 Ks[128][72];
  const int bh = blockIdx.y;
  const int b = bh >> 4;
  const int qb = blockIdx.x * 64;
  const int tid = threadIdx.x, lane = tid & 63, wid = tid >> 6;
  const int cc = lane & 15, gg = lane >> 4;
  const int qr0 = qb + wid * 16;
  const u16* qp = q_ws + ((size_t)bh * NQ + qr0 + cc) * DK + 8 * gg;
  const bf16x8 aq0 = *(const bf16x8*)qp;
  const bf16x8 aq1 = *(const bf16x8*)(qp + 32);
  float sum[4] = {0.f, 0.f, 0.f, 0.f};
  const int srow = tid >> 3, scol = 8 * (tid & 7);
  const f32x4 Z4 = {0.f, 0.f, 0.f, 0.f};
  for (int kc = 0; kc < NK; kc += 128) {
#pragma unroll
    for (int i = 0; i < 4; i++) {
      const u16* src = k_ws + ((size_t)bh * NK + kc + i * 32 + srow) * DK + scol;
      *(bf16x8*)&Ks[i * 32 + srow][scol] = *(const bf16x8*)src;
    }
    __syncthreads();
#pragma unroll 2
    for (int n = 0; n < 8; n++) {
      const bf16x8 b0 = *(const bf16x8*)&Ks[n * 16 + cc][8 * gg];
      const bf16x8 b1 = *(const bf16x8*)&Ks[n * 16 + cc][32 + 8 * gg];
      f32x4 acc = Z4;
      acc = MFMA(aq0, b0, acc);
      acc = MFMA(aq1, b1, acc);
      const int kcol = kc + n * 16 + cc;
      const size_t base = ((size_t)b * NQ + qr0 + 4 * gg) * NK + kcol;
#pragma unroll
      for (int r = 0; r < 4; r++) {
        const float wgt = attw[base + (size_t)r * NK];
        const int mk = amask[base + (size_t)r * NK];
        const float e = mk ? 0.f : EXP2F(acc[r] * wgt * EXPC);
        sum[r] += e;
      }
    }
    __syncthreads();
  }
#pragma unroll
  for (int r = 0; r < 4; r++) {
    float s = sum[r];
    s += __shfl_xor(s, 1);
    s += __shfl_xor(s, 2);
    s += __shfl_xor(s, 4);
    s += __shfl_xor(s, 8);
    if (cc == 0) l_ws[(size_t)bh * NQ + qr0 + 4 * gg + r] = s;
  }
}

// ---------------- K3: recompute logits, write att_softmax fp32, fused PV --------------
__global__ __launch_bounds__(256) void k_attn(
    const u16* __restrict__ q_ws, const u16* __restrict__ k_ws, const u16* __restrict__ vT_ws,
    const float* __restrict__ attw, const int* __restrict__ amask,
    const float* __restrict__ l_ws, float* __restrict__ att_out, u16* __restrict__ ctxb) {
  __shared__ u16 Ks[128][72];
  __shared__ u16 Vs[64][136];
  __shared__ u16 Ps[4][16][136];
  const int bh = blockIdx.y;
  const int b = bh >> 4, hh = bh & 15;
  const int qb = blockIdx.x * 64;
  const int tid = threadIdx.x, lane = tid & 63, wid = tid >> 6;
  const int cc = lane & 15, gg = lane >> 4;
  const int qr0 = qb + wid * 16;
  const u16* qp = q_ws + ((size_t)bh * NQ + qr0 + cc) * DK + 8 * gg;
  const bf16x8 aq0 = *(const bf16x8*)qp;
  const bf16x8 aq1 = *(const bf16x8*)(qp + 32);
  float rinv[4];
#pragma unroll
  for (int r = 0; r < 4; r++) {
    const float l = l_ws[(size_t)bh * NQ + qr0 + 4 * gg + r];
    rinv[r] = (l > 0.f) ? 1.0f / l : 0.f;  // guard: never triggers on valid mask
  }
  const f32x4 Z4 = {0.f, 0.f, 0.f, 0.f};
  f32x4 o[4];
#pragma unroll
  for (int i = 0; i < 4; i++) o[i] = Z4;
  float* attb = att_out + (size_t)bh * NQ * NK;
  const int srow = tid >> 3, scol = 8 * (tid & 7);

  for (int kc = 0; kc < NK; kc += 128) {
#pragma unroll
    for (int i = 0; i < 4; i++) {
      const u16* src = k_ws + ((size_t)bh * NK + kc + i * 32 + srow) * DK + scol;
      *(bf16x8*)&Ks[i * 32 + srow][scol] = *(const bf16x8*)src;
    }
#pragma unroll
    for (int i = 0; i < 4; i++) {
      const u16* src = vT_ws + ((size_t)bh * DK + i * 16 + (tid >> 4)) * NK + kc + (tid & 15) * 8;
      *(bf16x8*)&Vs[i * 16 + (tid >> 4)][(tid & 15) * 8] = *(const bf16x8*)src;
    }
    __syncthreads();
#pragma unroll 2
    for (int n = 0; n < 8; n++) {
      const bf16x8 b0 = *(const bf16x8*)&Ks[n * 16 + cc][8 * gg];
      const bf16x8 b1 = *(const bf16x8*)&Ks[n * 16 + cc][32 + 8 * gg];
      f32x4 acc = Z4;
      acc = MFMA(aq0, b0, acc);
      acc = MFMA(aq1, b1, acc);
      const int kcol = kc + n * 16 + cc;
      const size_t base = ((size_t)b * NQ + qr0 + 4 * gg) * NK + kcol;
#pragma unroll
      for (int r = 0; r < 4; r++) {
        const float wgt = attw[base + (size_t)r * NK];
        const int mk = amask[base + (size_t)r * NK];
        const float e = mk ? 0.f : EXP2F(acc[r] * wgt * EXPC);
        const float pv = e * rinv[r];
        attb[(size_t)(qr0 + 4 * gg + r) * NK + kcol] = pv;
        Ps[wid][4 * gg + r][n * 16 + cc] = f2bf(pv);
      }
    }
    // PV: O[16q x 64d] += P[16q x 128k] * V[128k x 64d]
    bf16x8 pa[4];
#pragma unroll
    for (int ks = 0; ks < 4; ks++) pa[ks] = *(const bf16x8*)&Ps[wid][cc][ks * 32 + 8 * gg];
#pragma unroll
    for (int nd = 0; nd < 4; nd++)
#pragma unroll
      for (int ks = 0; ks < 4; ks++) {
        const bf16x8 vb = *(const bf16x8*)&Vs[nd * 16 + cc][ks * 32 + 8 * gg];
        o[nd] = MFMA(pa[ks], vb, o[nd]);
      }
    __syncthreads();
  }
#pragma unroll
  for (int nd = 0; nd < 4; nd++)
#pragma unroll
    for (int r = 0; r < 4; r++)
      ctxb[((size_t)b * NQ + qr0 + 4 * gg + r) * DM + hh * 64 + nd * 16 + cc] = f2bf(o[nd][r]);
}

// ---------------- K4: out_final = ctx @ Wo^T + bo (fp32 out) --------------------------
__global__ __launch_bounds__(256) void k_oproj(
    const u16* __restrict__ ctxb, const u16* __restrict__ wob,
    const float* __restrict__ bo, float* __restrict__ outp) {
  __shared__ u16 As[2 * 4096];
  __shared__ u16 Bs[2 * 4096];
  const int tm = blockIdx.x * 128, tn = blockIdx.y * 128;
  f32x4 acc[4][4];
  gemm_core(ctxb, wob, tm, tn, As, Bs, acc);
  const int lane = threadIdx.x & 63;
  const int wid = threadIdx.x >> 6;
  const int wm = (wid >> 1) * 64, wn = (wid & 1) * 64;
  const int cc = lane & 15, gg = lane >> 4;
#pragma unroll
  for (int mi = 0; mi < 4; mi++) {
    const int rl = tm + wm + mi * 16 + 4 * gg;
#pragma unroll
    for (int ni = 0; ni < 4; ni++) {
      const int col = tn + wn + ni * 16 + cc;
      const float bs = bo[col];
      f32x4 a = acc[mi][ni];
#pragma unroll
      for (int r = 0; r < 4; r++) outp[(size_t)(rl + r) * DM + col] = a[r] + bs;
    }
  }
}

extern "C" void kernel_launch(void* const* d_in, const int* in_sizes, int n_in,
                              void* d_out, int out_size, void* d_ws, size_t ws_size,
                              hipStream_t stream) {
  (void)in_sizes; (void)n_in; (void)out_size; (void)ws_size;
  const float* queries = (const float*)d_in[0];
  const float* keys    = (const float*)d_in[1];
  const float* values  = (const float*)d_in[2];
  const float* qmask   = (const float*)d_in[3];
  const float* kmask   = (const float*)d_in[4];
  const int*   amask   = (const int*)d_in[5];   // bool -> int32 on device
  const float* attw    = (const float*)d_in[6];
  const float* Wq = (const float*)d_in[7];
  const float* Wk = (const float*)d_in[8];
  const float* Wv = (const float*)d_in[9];
  const float* Wo = (const float*)d_in[10];
  const float* bq = (const float*)d_in[11];
  const float* bk = (const float*)d_in[12];
  const float* bv = (const float*)d_in[13];
  const float* bo = (const float*)d_in[14];

  float* outf = (float*)d_out;
  float* att_out = outf + (size_t)4194304;

  // persistent scratch in d_ws: 34.25 MiB
  // (everything here is either consumed after k_attn or alive across it)
  char* p = (char*)d_ws;
  u16* q_ws  = (u16*)p; p += (size_t)4194304 * 2;
  u16* k_ws  = (u16*)p; p += (size_t)4194304 * 2;
  u16* vT_ws = (u16*)p; p += (size_t)4194304 * 2;
  u16* ctxb  = (u16*)p; p += (size_t)4194304 * 2;
  u16* wob   = (u16*)p; p += (size_t)1048576 * 2;  // read by k_oproj AFTER k_attn -> must persist
  float* l_ws = (float*)p; p += (size_t)65536 * 4;

  // transient bf16 copies (all consumed by k_proj, BEFORE k_attn clobbers att region)
  char* t = (char*)att_out;
  u16* xq  = (u16*)t; t += (size_t)4194304 * 2;
  u16* xk  = (u16*)t; t += (size_t)4194304 * 2;
  u16* xv  = (u16*)t; t += (size_t)4194304 * 2;
  u16* wqb = (u16*)t; t += (size_t)1048576 * 2;
  u16* wkb = (u16*)t; t += (size_t)1048576 * 2;
  u16* wvb = (u16*)t; t += (size_t)1048576 * 2;

  k_convert<<<dim3(4096, 7, 1), 256, 0, stream>>>(queries, keys, values, Wq, Wk, Wv, Wo,
                                                  xq, xk, xv, wqb, wkb, wvb, wob);
  k_proj<<<dim3(32, 8, 3), 256, 0, stream>>>(xq, xk, xv, wqb, wkb, wvb, bq, bk, bv,
                                             qmask, kmask, q_ws, k_ws, vT_ws);
  k_stats<<<dim3(32, 32, 1), 256, 0, stream>>>(q_ws, k_ws, attw, amask, l_ws);
  k_attn<<<dim3(32, 32, 1), 256, 0, stream>>>(q_ws, k_ws, vT_ws, attw, amask, l_ws,
                                              att_out, ctxb);
  k_oproj<<<dim3(32, 8, 1), 256, 0, stream>>>(ctxb, wob, bo, outf);
}

// Round 5
// 493.856 us; speedup vs baseline: 2.1215x; 2.1215x over previous
//
#include <hip/hip_runtime.h>

#define B2 2
#define NQ 2048
#define NK 2048
#define DM 1024
#define NH 16
#define DK 64
#define KC 64

typedef unsigned short u16;
typedef __attribute__((ext_vector_type(8))) short bf16x8;
typedef __attribute__((ext_vector_type(4))) float f32x4;

__device__ __forceinline__ u16 f2bf(float f) {
  unsigned u = __float_as_uint(f);
  u += 0x7FFFu + ((u >> 16) & 1u);
  return (u16)(u >> 16);
}

#if __has_builtin(__builtin_amdgcn_exp2f)
#define EXP2F(x) __builtin_amdgcn_exp2f(x)
#else
#define EXP2F(x) exp2f(x)
#endif

#define MFMA(a, b, c) __builtin_amdgcn_mfma_f32_16x16x32_bf16(a, b, c, 0, 0, 0)

// exp(x*wgt/8) = exp2(x*wgt*log2(e)/8)
#define EXPC 0.18033688011112043f

// ---------------- K0: fp32 -> bf16 convert (3 x 4M activations, 4 x 1M weights) ---------
__global__ __launch_bounds__(256) void k_convert(
    const float* __restrict__ s0, const float* __restrict__ s1, const float* __restrict__ s2,
    const float* __restrict__ s3, const float* __restrict__ s4, const float* __restrict__ s5,
    const float* __restrict__ s6,
    u16* __restrict__ d0, u16* __restrict__ d1, u16* __restrict__ d2, u16* __restrict__ d3,
    u16* __restrict__ d4, u16* __restrict__ d5, u16* __restrict__ d6) {
  const int j = blockIdx.y;
  const int n = (j < 3) ? (4 * 1024 * 1024) : (1024 * 1024);
  const int i = (blockIdx.x * 256 + threadIdx.x) * 4;
  if (i >= n) return;
  const float* s = (j == 0) ? s0 : (j == 1) ? s1 : (j == 2) ? s2 : (j == 3) ? s3
                  : (j == 4) ? s4 : (j == 5) ? s5 : s6;
  u16* d = (j == 0) ? d0 : (j == 1) ? d1 : (j == 2) ? d2 : (j == 3) ? d3
          : (j == 4) ? d4 : (j == 5) ? d5 : d6;
  const float4 f = *(const float4*)(s + i);
  ushort4 o;
  o.x = f2bf(f.x); o.y = f2bf(f.y); o.z = f2bf(f.z); o.w = f2bf(f.w);
  *(ushort4*)(d + i) = o;
}

// ---------------- shared 128x128 bf16 GEMM core: Y = A[M,1024] * W[N,1024]^T -----------
__device__ __forceinline__ void gemm_core(
    const u16* __restrict__ A, const u16* __restrict__ Wm,
    int tm, int tn, u16* As, u16* Bs, f32x4 acc[4][4]) {
  const int tid = threadIdx.x;
  const int lane = tid & 63;
  const int wid = tid >> 6;
  const int wm = (wid >> 1) * 64, wn = (wid & 1) * 64;
  const int cc = lane & 15, gg = lane >> 4;
  const int srow = tid >> 2, scol = 8 * (tid & 3);
  const size_t ra0 = (size_t)(tm + srow) * DM + scol;
  const size_t ra1 = (size_t)(tm + 64 + srow) * DM + scol;
  const size_t rb0 = (size_t)(tn + srow) * DM + scol;
  const size_t rb1 = (size_t)(tn + 64 + srow) * DM + scol;
  const f32x4 Z4 = {0.f, 0.f, 0.f, 0.f};
#pragma unroll
  for (int i = 0; i < 4; i++)
#pragma unroll
    for (int j = 0; j < 4; j++) acc[i][j] = Z4;

  *(bf16x8*)&As[tid * 8]        = *(const bf16x8*)(A + ra0);
  *(bf16x8*)&As[2048 + tid * 8] = *(const bf16x8*)(A + ra1);
  *(bf16x8*)&Bs[tid * 8]        = *(const bf16x8*)(Wm + rb0);
  *(bf16x8*)&Bs[2048 + tid * 8] = *(const bf16x8*)(Wm + rb1);

  int buf = 0;
  for (int kk = 0; kk < DM; kk += 32) {
    __syncthreads();
    const int o = buf * 4096;
    bf16x8 af[4], bv[4];
#pragma unroll
    for (int i = 0; i < 4; i++) af[i] = *(const bf16x8*)&As[o + (wm + i * 16 + cc) * 32 + 8 * gg];
#pragma unroll
    for (int i = 0; i < 4; i++) bv[i] = *(const bf16x8*)&Bs[o + (wn + i * 16 + cc) * 32 + 8 * gg];
    if (kk + 32 < DM) {
      const int p = (buf ^ 1) * 4096;
      *(bf16x8*)&As[p + tid * 8]        = *(const bf16x8*)(A + ra0 + kk + 32);
      *(bf16x8*)&As[p + 2048 + tid * 8] = *(const bf16x8*)(A + ra1 + kk + 32);
      *(bf16x8*)&Bs[p + tid * 8]        = *(const bf16x8*)(Wm + rb0 + kk + 32);
      *(bf16x8*)&Bs[p + 2048 + tid * 8] = *(const bf16x8*)(Wm + rb1 + kk + 32);
    }
#pragma unroll
    for (int mi = 0; mi < 4; mi++)
#pragma unroll
      for (int ni = 0; ni < 4; ni++) acc[mi][ni] = MFMA(af[mi], bv[ni], acc[mi][ni]);
    buf ^= 1;
  }
}

// ---------------- K1: QKV projections (z = 0/1/2 -> q/k/v), masked, head-split bf16 ----
__global__ __launch_bounds__(256) void k_proj(
    const u16* __restrict__ xq, const u16* __restrict__ xk, const u16* __restrict__ xv,
    const u16* __restrict__ wqb, const u16* __restrict__ wkb, const u16* __restrict__ wvb,
    const float* __restrict__ bq, const float* __restrict__ bk, const float* __restrict__ bv,
    const float* __restrict__ qmask, const float* __restrict__ kmask,
    u16* __restrict__ q_ws, u16* __restrict__ k_ws, u16* __restrict__ vT_ws) {
  __shared__ u16 As[2 * 4096];
  __shared__ u16 Bs[2 * 4096];
  const int z = blockIdx.z;
  const u16* A = (z == 0) ? xq : (z == 1) ? xk : xv;
  const u16* Wm = (z == 0) ? wqb : (z == 1) ? wkb : wvb;
  const float* bias = (z == 0) ? bq : (z == 1) ? bk : bv;
  const float* rmask = (z == 0) ? qmask : kmask;
  const int tm = blockIdx.x * 128, tn = blockIdx.y * 128;
  f32x4 acc[4][4];
  gemm_core(A, Wm, tm, tn, As, Bs, acc);

  const int lane = threadIdx.x & 63;
  const int wid = threadIdx.x >> 6;
  const int wm = (wid >> 1) * 64, wn = (wid & 1) * 64;
  const int cc = lane & 15, gg = lane >> 4;
  const int b = tm >> 11;
  const int tok0 = tm & 2047;
#pragma unroll
  for (int mi = 0; mi < 4; mi++) {
    const int rl = wm + mi * 16 + 4 * gg;
    float rm[4];
#pragma unroll
    for (int r = 0; r < 4; r++) rm[r] = rmask[b * NQ + tok0 + rl + r];
#pragma unroll
    for (int ni = 0; ni < 4; ni++) {
      const int col = tn + wn + ni * 16 + cc;
      const int h = col >> 6, d = col & 63;
      const float bs = bias[col];
      f32x4 a = acc[mi][ni];
      if (z <= 1) {
        u16* dst = ((z == 0) ? q_ws : k_ws) +
                   ((size_t)(b * NH + h) * NQ + tok0 + rl) * DK + d;
#pragma unroll
        for (int r = 0; r < 4; r++) dst[(size_t)r * DK] = f2bf((a[r] + bs) * rm[r]);
      } else {
        ushort4 pk;
        pk.x = f2bf((a[0] + bs) * rm[0]);
        pk.y = f2bf((a[1] + bs) * rm[1]);
        pk.z = f2bf((a[2] + bs) * rm[2]);
        pk.w = f2bf((a[3] + bs) * rm[3]);
        *(ushort4*)(vT_ws + ((size_t)(b * NH + h) * DK + d) * NK + tok0 + rl) = pk;
      }
    }
  }
}

// ---------------- K2: softmax denominators l[b,h,q] = sum_k exp(logit) ----------------
// swapped mfma(K,Q): lane holds p[q=cc][k=16n+4gg+r] -> float4/int4 loads
__global__ __launch_bounds__(256) void k_stats(
    const u16* __restrict__ q_ws, const u16* __restrict__ k_ws,
    const float* __restrict__ attw, const int* __restrict__ amask,
    float* __restrict__ l_ws) {
  __shared__ u16 Ks[128][72];
  const int bh = blockIdx.y;
  const int b = bh >> 4;
  const int qb = blockIdx.x * 64;
  const int tid = threadIdx.x, lane = tid & 63, wid = tid >> 6;
  const int cc = lane & 15, gg = lane >> 4;
  const int qr0 = qb + wid * 16;
  const u16* qp = q_ws + ((size_t)bh * NQ + qr0 + cc) * DK + 8 * gg;
  const bf16x8 aq0 = *(const bf16x8*)qp;
  const bf16x8 aq1 = *(const bf16x8*)(qp + 32);
  const float* awrow = attw + ((size_t)b * NQ + qr0 + cc) * NK;
  const int* mkrow = amask + ((size_t)b * NQ + qr0 + cc) * NK;
  float sum = 0.f;
  const int sr = tid >> 3, sc = 8 * (tid & 7);
  const f32x4 Z4 = {0.f, 0.f, 0.f, 0.f};
  for (int kc = 0; kc < NK; kc += 128) {
#pragma unroll
    for (int i = 0; i < 4; i++)
      *(bf16x8*)&Ks[i * 32 + sr][sc] =
          *(const bf16x8*)(k_ws + ((size_t)bh * NK + kc + i * 32 + sr) * DK + sc);
    __syncthreads();
#pragma unroll
    for (int n = 0; n < 8; n++) {
      const bf16x8 k0 = *(const bf16x8*)&Ks[n * 16 + cc][8 * gg];
      const bf16x8 k1 = *(const bf16x8*)&Ks[n * 16 + cc][32 + 8 * gg];
      f32x4 acc = Z4;
      acc = MFMA(k0, aq0, acc);
      acc = MFMA(k1, aq1, acc);
      const int k0i = kc + n * 16 + 4 * gg;
      const float4 wgt = *(const float4*)(awrow + k0i);
      const int4 mk = *(const int4*)(mkrow + k0i);
      sum += mk.x ? 0.f : EXP2F(acc[0] * wgt.x * EXPC);
      sum += mk.y ? 0.f : EXP2F(acc[1] * wgt.y * EXPC);
      sum += mk.z ? 0.f : EXP2F(acc[2] * wgt.z * EXPC);
      sum += mk.w ? 0.f : EXP2F(acc[3] * wgt.w * EXPC);
    }
    __syncthreads();
  }
  sum += __shfl_xor(sum, 16);
  sum += __shfl_xor(sum, 32);
  if (gg == 0) l_ws[(size_t)bh * NQ + qr0 + cc] = sum;
}

// ---------------- K3: recompute logits, write att_softmax fp32 (f32x4 nt), fused PV ---
__global__ __launch_bounds__(256) void k_attn(
    const u16* __restrict__ q_ws, const u16* __restrict__ k_ws, const u16* __restrict__ vT_ws,
    const float* __restrict__ attw, const int* __restrict__ amask,
    const float* __restrict__ l_ws, float* __restrict__ att_out, u16* __restrict__ ctxb) {
  __shared__ u16 Ks[KC][72];
  __shared__ u16 Vs[64][72];
  __shared__ u16 Ps[4][16][72];
  const int bh = blockIdx.y;
  const int b = bh >> 4, hh = bh & 15;
  const int qb = blockIdx.x * 64;
  const int tid = threadIdx.x, lane = tid & 63, wid = tid >> 6;
  const int cc = lane & 15, gg = lane >> 4;
  const int qr0 = qb + wid * 16;
  const u16* qp = q_ws + ((size_t)bh * NQ + qr0 + cc) * DK + 8 * gg;
  const bf16x8 aq0 = *(const bf16x8*)qp;
  const bf16x8 aq1 = *(const bf16x8*)(qp + 32);
  const float l = l_ws[(size_t)bh * NQ + qr0 + cc];
  const float rinv = (l > 0.f) ? 1.0f / l : 0.f;
  const f32x4 Z4 = {0.f, 0.f, 0.f, 0.f};
  f32x4 o[4];
#pragma unroll
  for (int i = 0; i < 4; i++) o[i] = Z4;
  const float* awrow = attw + ((size_t)b * NQ + qr0 + cc) * NK;
  const int* mkrow = amask + ((size_t)b * NQ + qr0 + cc) * NK;
  float* attrow = att_out + (size_t)bh * NQ * NK + (size_t)(qr0 + cc) * NK;
  const int sr = tid >> 3, sc = 8 * (tid & 7);

  for (int kc = 0; kc < NK; kc += KC) {
    // stage K[64k x 64d] and V^T[64d x 64k] (two 32-row passes each)
#pragma unroll
    for (int i = 0; i < 2; i++) {
      *(bf16x8*)&Ks[i * 32 + sr][sc] =
          *(const bf16x8*)(k_ws + ((size_t)bh * NK + kc + i * 32 + sr) * DK + sc);
      *(bf16x8*)&Vs[i * 32 + sr][sc] =
          *(const bf16x8*)(vT_ws + ((size_t)bh * DK + i * 32 + sr) * NK + kc + sc);
    }
    __syncthreads();
    // QK^T swapped: p[q=cc][k=16n+4gg+r]
#pragma unroll
    for (int n = 0; n < 4; n++) {
      const bf16x8 k0 = *(const bf16x8*)&Ks[n * 16 + cc][8 * gg];
      const bf16x8 k1 = *(const bf16x8*)&Ks[n * 16 + cc][32 + 8 * gg];
      f32x4 acc = Z4;
      acc = MFMA(k0, aq0, acc);
      acc = MFMA(k1, aq1, acc);
      const int k0i = kc + n * 16 + 4 * gg;
      const float4 wgt = *(const float4*)(awrow + k0i);
      const int4 mk = *(const int4*)(mkrow + k0i);
      f32x4 pv;
      pv.x = mk.x ? 0.f : EXP2F(acc[0] * wgt.x * EXPC) * rinv;
      pv.y = mk.y ? 0.f : EXP2F(acc[1] * wgt.y * EXPC) * rinv;
      pv.z = mk.z ? 0.f : EXP2F(acc[2] * wgt.z * EXPC) * rinv;
      pv.w = mk.w ? 0.f : EXP2F(acc[3] * wgt.w * EXPC) * rinv;
      __builtin_nontemporal_store(pv, (f32x4*)(attrow + k0i));
      ushort4 pk;
      pk.x = f2bf(pv.x); pk.y = f2bf(pv.y); pk.z = f2bf(pv.z); pk.w = f2bf(pv.w);
      *(ushort4*)&Ps[wid][cc][n * 16 + 4 * gg] = pk;  // per-wave buffer: no barrier needed
    }
    // PV: O[16q x 64d] += P[16q x 64k] * V[64k x 64d]
    const bf16x8 pa0 = *(const bf16x8*)&Ps[wid][cc][8 * gg];
    const bf16x8 pa1 = *(const bf16x8*)&Ps[wid][cc][32 + 8 * gg];
#pragma unroll
    for (int nd = 0; nd < 4; nd++) {
      const bf16x8 vb0 = *(const bf16x8*)&Vs[nd * 16 + cc][8 * gg];
      const bf16x8 vb1 = *(const bf16x8*)&Vs[nd * 16 + cc][32 + 8 * gg];
      o[nd] = MFMA(pa0, vb0, o[nd]);
      o[nd] = MFMA(pa1, vb1, o[nd]);
    }
    __syncthreads();
  }
  // PV C-layout unchanged: O[q=4gg+r][d=nd*16+cc]
#pragma unroll
  for (int nd = 0; nd < 4; nd++)
#pragma unroll
    for (int r = 0; r < 4; r++)
      ctxb[((size_t)b * NQ + qr0 + 4 * gg + r) * DM + hh * 64 + nd * 16 + cc] = f2bf(o[nd][r]);
}

// ---------------- K4: out_final = ctx @ Wo^T + bo (fp32 out) --------------------------
__global__ __launch_bounds__(256) void k_oproj(
    const u16* __restrict__ ctxb, const u16* __restrict__ wob,
    const float* __restrict__ bo, float* __restrict__ outp) {
  __shared__ u16 As[2 * 4096];
  __shared__ u16 Bs[2 * 4096];
  const int tm = blockIdx.x * 128, tn = blockIdx.y * 128;
  f32x4 acc[4][4];
  gemm_core(ctxb, wob, tm, tn, As, Bs, acc);
  const int lane = threadIdx.x & 63;
  const int wid = threadIdx.x >> 6;
  const int wm = (wid >> 1) * 64, wn = (wid & 1) * 64;
  const int cc = lane & 15, gg = lane >> 4;
#pragma unroll
  for (int mi = 0; mi < 4; mi++) {
    const int rl = tm + wm + mi * 16 + 4 * gg;
#pragma unroll
    for (int ni = 0; ni < 4; ni++) {
      const int col = tn + wn + ni * 16 + cc;
      const float bs = bo[col];
      f32x4 a = acc[mi][ni];
#pragma unroll
      for (int r = 0; r < 4; r++) outp[(size_t)(rl + r) * DM + col] = a[r] + bs;
    }
  }
}

extern "C" void kernel_launch(void* const* d_in, const int* in_sizes, int n_in,
                              void* d_out, int out_size, void* d_ws, size_t ws_size,
                              hipStream_t stream) {
  (void)in_sizes; (void)n_in; (void)out_size; (void)ws_size;
  const float* queries = (const float*)d_in[0];
  const float* keys    = (const float*)d_in[1];
  const float* values  = (const float*)d_in[2];
  const float* qmask   = (const float*)d_in[3];
  const float* kmask   = (const float*)d_in[4];
  const int*   amask   = (const int*)d_in[5];   // bool -> int32 on device
  const float* attw    = (const float*)d_in[6];
  const float* Wq = (const float*)d_in[7];
  const float* Wk = (const float*)d_in[8];
  const float* Wv = (const float*)d_in[9];
  const float* Wo = (const float*)d_in[10];
  const float* bq = (const float*)d_in[11];
  const float* bk = (const float*)d_in[12];
  const float* bv = (const float*)d_in[13];
  const float* bo = (const float*)d_in[14];

  float* outf = (float*)d_out;
  float* att_out = outf + (size_t)4194304;

  // persistent scratch in d_ws: 34.25 MiB
  char* p = (char*)d_ws;
  u16* q_ws  = (u16*)p; p += (size_t)4194304 * 2;
  u16* k_ws  = (u16*)p; p += (size_t)4194304 * 2;
  u16* vT_ws = (u16*)p; p += (size_t)4194304 * 2;
  u16* ctxb  = (u16*)p; p += (size_t)4194304 * 2;
  u16* wob   = (u16*)p; p += (size_t)1048576 * 2;  // read by k_oproj AFTER k_attn -> persist
  float* l_ws = (float*)p; p += (size_t)65536 * 4;

  // transient bf16 copies (all consumed by k_proj, BEFORE k_attn clobbers att region)
  char* t = (char*)att_out;
  u16* xq  = (u16*)t; t += (size_t)4194304 * 2;
  u16* xk  = (u16*)t; t += (size_t)4194304 * 2;
  u16* xv  = (u16*)t; t += (size_t)4194304 * 2;
  u16* wqb = (u16*)t; t += (size_t)1048576 * 2;
  u16* wkb = (u16*)t; t += (size_t)1048576 * 2;
  u16* wvb = (u16*)t; t += (size_t)1048576 * 2;

  k_convert<<<dim3(4096, 7, 1), 256, 0, stream>>>(queries, keys, values, Wq, Wk, Wv, Wo,
                                                  xq, xk, xv, wqb, wkb, wvb, wob);
  k_proj<<<dim3(32, 8, 3), 256, 0, stream>>>(xq, xk, xv, wqb, wkb, wvb, bq, bk, bv,
                                             qmask, kmask, q_ws, k_ws, vT_ws);
  k_stats<<<dim3(32, 32, 1), 256, 0, stream>>>(q_ws, k_ws, attw, amask, l_ws);
  k_attn<<<dim3(32, 32, 1), 256, 0, stream>>>(q_ws, k_ws, vT_ws, attw, amask, l_ws,
                                              att_out, ctxb);
  k_oproj<<<dim3(32, 8, 1), 256, 0, stream>>>(ctxb, wob, bo, outf);
}

// Round 6
// 438.277 us; speedup vs baseline: 2.3905x; 1.1268x over previous
//
#include <hip/hip_runtime.h>

#define B2 2
#define NQ 2048
#define NK 2048
#define DM 1024
#define NH 16
#define DK 64
#define KC 64

typedef unsigned short u16;
typedef __attribute__((ext_vector_type(8))) short bf16x8;
typedef __attribute__((ext_vector_type(4))) float f32x4;

__device__ __forceinline__ u16 f2bf(float f) {
  unsigned u = __float_as_uint(f);
  u += 0x7FFFu + ((u >> 16) & 1u);
  return (u16)(u >> 16);
}
__device__ __forceinline__ float bf2f(u16 u) {
  return __uint_as_float(((unsigned)u) << 16);
}

#if __has_builtin(__builtin_amdgcn_exp2f)
#define EXP2F(x) __builtin_amdgcn_exp2f(x)
#else
#define EXP2F(x) exp2f(x)
#endif

#define MFMA(a, b, c) __builtin_amdgcn_mfma_f32_16x16x32_bf16(a, b, c, 0, 0, 0)

// exp(x*wgt/8) = exp2(x*wgt*log2(e)/8)
#define EXPC 0.18033688011112043f

// ---------------- K0: fp32 -> bf16 convert (3 x 4M activations, 4 x 1M weights) ---------
__global__ __launch_bounds__(256) void k_convert(
    const float* __restrict__ s0, const float* __restrict__ s1, const float* __restrict__ s2,
    const float* __restrict__ s3, const float* __restrict__ s4, const float* __restrict__ s5,
    const float* __restrict__ s6,
    u16* __restrict__ d0, u16* __restrict__ d1, u16* __restrict__ d2, u16* __restrict__ d3,
    u16* __restrict__ d4, u16* __restrict__ d5, u16* __restrict__ d6) {
  const int j = blockIdx.y;
  const int n = (j < 3) ? (4 * 1024 * 1024) : (1024 * 1024);
  const int i = (blockIdx.x * 256 + threadIdx.x) * 4;
  if (i >= n) return;
  const float* s = (j == 0) ? s0 : (j == 1) ? s1 : (j == 2) ? s2 : (j == 3) ? s3
                  : (j == 4) ? s4 : (j == 5) ? s5 : s6;
  u16* d = (j == 0) ? d0 : (j == 1) ? d1 : (j == 2) ? d2 : (j == 3) ? d3
          : (j == 4) ? d4 : (j == 5) ? d5 : d6;
  const float4 f = *(const float4*)(s + i);
  ushort4 o;
  o.x = f2bf(f.x); o.y = f2bf(f.y); o.z = f2bf(f.z); o.w = f2bf(f.w);
  *(ushort4*)(d + i) = o;
}

// ---------------- K0b: fw[b,q,k] = amask ? NaN : bf16(attw)  (the fused mask+weight) ---
__global__ __launch_bounds__(256) void k_fuse(
    const float* __restrict__ attw, const int* __restrict__ amask, u16* __restrict__ fw) {
  const int i = (blockIdx.x * 256 + threadIdx.x) * 4;
  const float4 w = *(const float4*)(attw + i);
  const int4 m = *(const int4*)(amask + i);
  ushort4 o;
  o.x = m.x ? 0x7FC0 : f2bf(w.x);
  o.y = m.y ? 0x7FC0 : f2bf(w.y);
  o.z = m.z ? 0x7FC0 : f2bf(w.z);
  o.w = m.w ? 0x7FC0 : f2bf(w.w);
  *(ushort4*)(fw + i) = o;
}

// ---------------- shared 128x128 bf16 GEMM core: Y = A[M,1024] * W[N,1024]^T -----------
__device__ __forceinline__ void gemm_core(
    const u16* __restrict__ A, const u16* __restrict__ Wm,
    int tm, int tn, u16* As, u16* Bs, f32x4 acc[4][4]) {
  const int tid = threadIdx.x;
  const int lane = tid & 63;
  const int wid = tid >> 6;
  const int wm = (wid >> 1) * 64, wn = (wid & 1) * 64;
  const int cc = lane & 15, gg = lane >> 4;
  const int srow = tid >> 2, scol = 8 * (tid & 3);
  const size_t ra0 = (size_t)(tm + srow) * DM + scol;
  const size_t ra1 = (size_t)(tm + 64 + srow) * DM + scol;
  const size_t rb0 = (size_t)(tn + srow) * DM + scol;
  const size_t rb1 = (size_t)(tn + 64 + srow) * DM + scol;
  const f32x4 Z4 = {0.f, 0.f, 0.f, 0.f};
#pragma unroll
  for (int i = 0; i < 4; i++)
#pragma unroll
    for (int j = 0; j < 4; j++) acc[i][j] = Z4;

  *(bf16x8*)&As[tid * 8]        = *(const bf16x8*)(A + ra0);
  *(bf16x8*)&As[2048 + tid * 8] = *(const bf16x8*)(A + ra1);
  *(bf16x8*)&Bs[tid * 8]        = *(const bf16x8*)(Wm + rb0);
  *(bf16x8*)&Bs[2048 + tid * 8] = *(const bf16x8*)(Wm + rb1);

  int buf = 0;
  for (int kk = 0; kk < DM; kk += 32) {
    __syncthreads();
    const int o = buf * 4096;
    bf16x8 af[4], bv[4];
#pragma unroll
    for (int i = 0; i < 4; i++) af[i] = *(const bf16x8*)&As[o + (wm + i * 16 + cc) * 32 + 8 * gg];
#pragma unroll
    for (int i = 0; i < 4; i++) bv[i] = *(const bf16x8*)&Bs[o + (wn + i * 16 + cc) * 32 + 8 * gg];
    if (kk + 32 < DM) {
      const int p = (buf ^ 1) * 4096;
      *(bf16x8*)&As[p + tid * 8]        = *(const bf16x8*)(A + ra0 + kk + 32);
      *(bf16x8*)&As[p + 2048 + tid * 8] = *(const bf16x8*)(A + ra1 + kk + 32);
      *(bf16x8*)&Bs[p + tid * 8]        = *(const bf16x8*)(Wm + rb0 + kk + 32);
      *(bf16x8*)&Bs[p + 2048 + tid * 8] = *(const bf16x8*)(Wm + rb1 + kk + 32);
    }
#pragma unroll
    for (int mi = 0; mi < 4; mi++)
#pragma unroll
      for (int ni = 0; ni < 4; ni++) acc[mi][ni] = MFMA(af[mi], bv[ni], acc[mi][ni]);
    buf ^= 1;
  }
}

// ---------------- K1: QKV projections (z = 0/1/2 -> q/k/v), masked, head-split bf16 ----
__global__ __launch_bounds__(256) void k_proj(
    const u16* __restrict__ xq, const u16* __restrict__ xk, const u16* __restrict__ xv,
    const u16* __restrict__ wqb, const u16* __restrict__ wkb, const u16* __restrict__ wvb,
    const float* __restrict__ bq, const float* __restrict__ bk, const float* __restrict__ bv,
    const float* __restrict__ qmask, const float* __restrict__ kmask,
    u16* __restrict__ q_ws, u16* __restrict__ k_ws, u16* __restrict__ vT_ws) {
  __shared__ u16 As[2 * 4096];
  __shared__ u16 Bs[2 * 4096];
  const int z = blockIdx.z;
  const u16* A = (z == 0) ? xq : (z == 1) ? xk : xv;
  const u16* Wm = (z == 0) ? wqb : (z == 1) ? wkb : wvb;
  const float* bias = (z == 0) ? bq : (z == 1) ? bk : bv;
  const float* rmask = (z == 0) ? qmask : kmask;
  const int tm = blockIdx.x * 128, tn = blockIdx.y * 128;
  f32x4 acc[4][4];
  gemm_core(A, Wm, tm, tn, As, Bs, acc);

  const int lane = threadIdx.x & 63;
  const int wid = threadIdx.x >> 6;
  const int wm = (wid >> 1) * 64, wn = (wid & 1) * 64;
  const int cc = lane & 15, gg = lane >> 4;
  const int b = tm >> 11;
  const int tok0 = tm & 2047;
#pragma unroll
  for (int mi = 0; mi < 4; mi++) {
    const int rl = wm + mi * 16 + 4 * gg;
    float rm[4];
#pragma unroll
    for (int r = 0; r < 4; r++) rm[r] = rmask[b * NQ + tok0 + rl + r];
#pragma unroll
    for (int ni = 0; ni < 4; ni++) {
      const int col = tn + wn + ni * 16 + cc;
      const int h = col >> 6, d = col & 63;
      const float bs = bias[col];
      f32x4 a = acc[mi][ni];
      if (z <= 1) {
        u16* dst = ((z == 0) ? q_ws : k_ws) +
                   ((size_t)(b * NH + h) * NQ + tok0 + rl) * DK + d;
#pragma unroll
        for (int r = 0; r < 4; r++) dst[(size_t)r * DK] = f2bf((a[r] + bs) * rm[r]);
      } else {
        ushort4 pk;
        pk.x = f2bf((a[0] + bs) * rm[0]);
        pk.y = f2bf((a[1] + bs) * rm[1]);
        pk.z = f2bf((a[2] + bs) * rm[2]);
        pk.w = f2bf((a[3] + bs) * rm[3]);
        *(ushort4*)(vT_ws + ((size_t)(b * NH + h) * DK + d) * NK + tok0 + rl) = pk;
      }
    }
  }
}

// ---------------- K2: softmax denominators l[b,h,q] = sum_k exp(logit), fw-driven -----
__global__ __launch_bounds__(256) void k_stats(
    const u16* __restrict__ q_ws, const u16* __restrict__ k_ws,
    const u16* __restrict__ fw, float* __restrict__ l_ws) {
  __shared__ u16 Ks[128][72];
  const int bh = blockIdx.y;
  const int b = bh >> 4;
  const int qb = blockIdx.x * 64;
  const int tid = threadIdx.x, lane = tid & 63, wid = tid >> 6;
  const int cc = lane & 15, gg = lane >> 4;
  const int qr0 = qb + wid * 16;
  const u16* qp = q_ws + ((size_t)bh * NQ + qr0 + cc) * DK + 8 * gg;
  const bf16x8 aq0 = *(const bf16x8*)qp;
  const bf16x8 aq1 = *(const bf16x8*)(qp + 32);
  const u16* fwrow = fw + ((size_t)b * NQ + qr0 + cc) * NK;
  float sum = 0.f;
  const int sr = tid >> 3, sc = 8 * (tid & 7);
  const f32x4 Z4 = {0.f, 0.f, 0.f, 0.f};
  for (int kc = 0; kc < NK; kc += 128) {
#pragma unroll
    for (int i = 0; i < 4; i++)
      *(bf16x8*)&Ks[i * 32 + sr][sc] =
          *(const bf16x8*)(k_ws + ((size_t)bh * NK + kc + i * 32 + sr) * DK + sc);
    __syncthreads();
#pragma unroll
    for (int n = 0; n < 8; n++) {
      const bf16x8 k0 = *(const bf16x8*)&Ks[n * 16 + cc][8 * gg];
      const bf16x8 k1 = *(const bf16x8*)&Ks[n * 16 + cc][32 + 8 * gg];
      f32x4 acc = Z4;
      acc = MFMA(k0, aq0, acc);
      acc = MFMA(k1, aq1, acc);
      const int k0i = kc + n * 16 + 4 * gg;
      const ushort4 fv = *(const ushort4*)(fwrow + k0i);
      const float e0 = EXP2F(acc[0] * bf2f(fv.x) * EXPC);
      const float e1 = EXP2F(acc[1] * bf2f(fv.y) * EXPC);
      const float e2 = EXP2F(acc[2] * bf2f(fv.z) * EXPC);
      const float e3 = EXP2F(acc[3] * bf2f(fv.w) * EXPC);
      sum += (e0 == e0) ? e0 : 0.f;   // NaN w (masked) -> contributes 0
      sum += (e1 == e1) ? e1 : 0.f;
      sum += (e2 == e2) ? e2 : 0.f;
      sum += (e3 == e3) ? e3 : 0.f;
    }
    __syncthreads();
  }
  sum += __shfl_xor(sum, 16);
  sum += __shfl_xor(sum, 32);
  if (gg == 0) l_ws[(size_t)bh * NQ + qr0 + cc] = sum;
}

// ---------------- K3: recompute logits, write att_softmax fp32 (f32x4 nt), fused PV ---
__global__ __launch_bounds__(256) void k_attn(
    const u16* __restrict__ q_ws, const u16* __restrict__ k_ws, const u16* __restrict__ vT_ws,
    const u16* __restrict__ fw, const float* __restrict__ l_ws,
    float* __restrict__ att_out, u16* __restrict__ ctxb) {
  __shared__ u16 Ks[KC][72];
  __shared__ u16 Vs[64][72];
  __shared__ u16 Ps[4][16][72];
  const int bh = blockIdx.y;
  const int b = bh >> 4, hh = bh & 15;
  const int qb = blockIdx.x * 64;
  const int tid = threadIdx.x, lane = tid & 63, wid = tid >> 6;
  const int cc = lane & 15, gg = lane >> 4;
  const int qr0 = qb + wid * 16;
  const u16* qp = q_ws + ((size_t)bh * NQ + qr0 + cc) * DK + 8 * gg;
  const bf16x8 aq0 = *(const bf16x8*)qp;
  const bf16x8 aq1 = *(const bf16x8*)(qp + 32);
  const float l = l_ws[(size_t)bh * NQ + qr0 + cc];
  const float rinv = (l > 0.f) ? 1.0f / l : 0.f;
  const f32x4 Z4 = {0.f, 0.f, 0.f, 0.f};
  f32x4 o[4];
#pragma unroll
  for (int i = 0; i < 4; i++) o[i] = Z4;
  const u16* fwrow = fw + ((size_t)b * NQ + qr0 + cc) * NK;
  float* attrow = att_out + (size_t)bh * NQ * NK + (size_t)(qr0 + cc) * NK;
  const int sr = tid >> 3, sc = 8 * (tid & 7);

  for (int kc = 0; kc < NK; kc += KC) {
#pragma unroll
    for (int i = 0; i < 2; i++) {
      *(bf16x8*)&Ks[i * 32 + sr][sc] =
          *(const bf16x8*)(k_ws + ((size_t)bh * NK + kc + i * 32 + sr) * DK + sc);
      *(bf16x8*)&Vs[i * 32 + sr][sc] =
          *(const bf16x8*)(vT_ws + ((size_t)bh * DK + i * 32 + sr) * NK + kc + sc);
    }
    __syncthreads();
    // QK^T swapped: p[q=cc][k=16n+4gg+r]
#pragma unroll
    for (int n = 0; n < 4; n++) {
      const bf16x8 k0 = *(const bf16x8*)&Ks[n * 16 + cc][8 * gg];
      const bf16x8 k1 = *(const bf16x8*)&Ks[n * 16 + cc][32 + 8 * gg];
      f32x4 acc = Z4;
      acc = MFMA(k0, aq0, acc);
      acc = MFMA(k1, aq1, acc);
      const int k0i = kc + n * 16 + 4 * gg;
      const ushort4 fv = *(const ushort4*)(fwrow + k0i);
      const float e0 = EXP2F(acc[0] * bf2f(fv.x) * EXPC);
      const float e1 = EXP2F(acc[1] * bf2f(fv.y) * EXPC);
      const float e2 = EXP2F(acc[2] * bf2f(fv.z) * EXPC);
      const float e3 = EXP2F(acc[3] * bf2f(fv.w) * EXPC);
      f32x4 pv;
      pv.x = (e0 == e0) ? e0 * rinv : 0.f;
      pv.y = (e1 == e1) ? e1 * rinv : 0.f;
      pv.z = (e2 == e2) ? e2 * rinv : 0.f;
      pv.w = (e3 == e3) ? e3 * rinv : 0.f;
      __builtin_nontemporal_store(pv, (f32x4*)(attrow + k0i));
      ushort4 pk;
      pk.x = f2bf(pv.x); pk.y = f2bf(pv.y); pk.z = f2bf(pv.z); pk.w = f2bf(pv.w);
      *(ushort4*)&Ps[wid][cc][n * 16 + 4 * gg] = pk;  // per-wave buffer: no barrier needed
    }
    // PV: O[16q x 64d] += P[16q x 64k] * V[64k x 64d]
    const bf16x8 pa0 = *(const bf16x8*)&Ps[wid][cc][8 * gg];
    const bf16x8 pa1 = *(const bf16x8*)&Ps[wid][cc][32 + 8 * gg];
#pragma unroll
    for (int nd = 0; nd < 4; nd++) {
      const bf16x8 vb0 = *(const bf16x8*)&Vs[nd * 16 + cc][8 * gg];
      const bf16x8 vb1 = *(const bf16x8*)&Vs[nd * 16 + cc][32 + 8 * gg];
      o[nd] = MFMA(pa0, vb0, o[nd]);
      o[nd] = MFMA(pa1, vb1, o[nd]);
    }
    __syncthreads();
  }
  // PV C-layout: O[q=4gg+r][d=nd*16+cc]
#pragma unroll
  for (int nd = 0; nd < 4; nd++)
#pragma unroll
    for (int r = 0; r < 4; r++)
      ctxb[((size_t)b * NQ + qr0 + 4 * gg + r) * DM + hh * 64 + nd * 16 + cc] = f2bf(o[nd][r]);
}

// ---------------- K4: out_final = ctx @ Wo^T + bo (fp32 out) --------------------------
__global__ __launch_bounds__(256) void k_oproj(
    const u16* __restrict__ ctxb, const u16* __restrict__ wob,
    const float* __restrict__ bo, float* __restrict__ outp) {
  __shared__ u16 As[2 * 4096];
  __shared__ u16 Bs[2 * 4096];
  const int tm = blockIdx.x * 128, tn = blockIdx.y * 128;
  f32x4 acc[4][4];
  gemm_core(ctxb, wob, tm, tn, As, Bs, acc);
  const int lane = threadIdx.x & 63;
  const int wid = threadIdx.x >> 6;
  const int wm = (wid >> 1) * 64, wn = (wid & 1) * 64;
  const int cc = lane & 15, gg = lane >> 4;
#pragma unroll
  for (int mi = 0; mi < 4; mi++) {
    const int rl = tm + wm + mi * 16 + 4 * gg;
#pragma unroll
    for (int ni = 0; ni < 4; ni++) {
      const int col = tn + wn + ni * 16 + cc;
      const float bs = bo[col];
      f32x4 a = acc[mi][ni];
#pragma unroll
      for (int r = 0; r < 4; r++) outp[(size_t)(rl + r) * DM + col] = a[r] + bs;
    }
  }
}

extern "C" void kernel_launch(void* const* d_in, const int* in_sizes, int n_in,
                              void* d_out, int out_size, void* d_ws, size_t ws_size,
                              hipStream_t stream) {
  (void)in_sizes; (void)n_in; (void)out_size; (void)ws_size;
  const float* queries = (const float*)d_in[0];
  const float* keys    = (const float*)d_in[1];
  const float* values  = (const float*)d_in[2];
  const float* qmask   = (const float*)d_in[3];
  const float* kmask   = (const float*)d_in[4];
  const int*   amask   = (const int*)d_in[5];   // bool -> int32 on device
  const float* attw    = (const float*)d_in[6];
  const float* Wq = (const float*)d_in[7];
  const float* Wk = (const float*)d_in[8];
  const float* Wv = (const float*)d_in[9];
  const float* Wo = (const float*)d_in[10];
  const float* bq = (const float*)d_in[11];
  const float* bk = (const float*)d_in[12];
  const float* bv = (const float*)d_in[13];
  const float* bo = (const float*)d_in[14];

  float* outf = (float*)d_out;
  float* att_out = outf + (size_t)4194304;

  // persistent scratch in d_ws: 51.3 MiB
  char* p = (char*)d_ws;
  u16* q_ws  = (u16*)p; p += (size_t)4194304 * 2;
  u16* k_ws  = (u16*)p; p += (size_t)4194304 * 2;
  u16* vT_ws = (u16*)p; p += (size_t)4194304 * 2;
  u16* ctxb  = (u16*)p; p += (size_t)4194304 * 2;
  u16* wob   = (u16*)p; p += (size_t)1048576 * 2;  // read by k_oproj AFTER k_attn -> persist
  float* l_ws = (float*)p; p += (size_t)65536 * 4;
  u16* fw    = (u16*)p; p += (size_t)8388608 * 2;  // fused mask+weight, read by stats+attn

  // transient bf16 copies (all consumed by k_proj, BEFORE k_attn clobbers att region)
  char* t = (char*)att_out;
  u16* xq  = (u16*)t; t += (size_t)4194304 * 2;
  u16* xk  = (u16*)t; t += (size_t)4194304 * 2;
  u16* xv  = (u16*)t; t += (size_t)4194304 * 2;
  u16* wqb = (u16*)t; t += (size_t)1048576 * 2;
  u16* wkb = (u16*)t; t += (size_t)1048576 * 2;
  u16* wvb = (u16*)t; t += (size_t)1048576 * 2;

  k_convert<<<dim3(4096, 7, 1), 256, 0, stream>>>(queries, keys, values, Wq, Wk, Wv, Wo,
                                                  xq, xk, xv, wqb, wkb, wvb, wob);
  k_fuse<<<dim3(8192, 1, 1), 256, 0, stream>>>(attw, amask, fw);
  k_proj<<<dim3(32, 8, 3), 256, 0, stream>>>(xq, xk, xv, wqb, wkb, wvb, bq, bk, bv,
                                             qmask, kmask, q_ws, k_ws, vT_ws);
  k_stats<<<dim3(32, 32, 1), 256, 0, stream>>>(q_ws, k_ws, fw, l_ws);
  k_attn<<<dim3(32, 32, 1), 256, 0, stream>>>(q_ws, k_ws, vT_ws, fw, l_ws,
                                              att_out, ctxb);
  k_oproj<<<dim3(32, 8, 1), 256, 0, stream>>>(ctxb, wob, bo, outf);
}

// Round 7
// 326.870 us; speedup vs baseline: 3.2053x; 1.3408x over previous
//
#include <hip/hip_runtime.h>

#define B2 2
#define NQ 2048
#define NK 2048
#define DM 1024
#define NH 16
#define DK 64
#define KC 64

typedef unsigned short u16;
typedef __attribute__((ext_vector_type(8))) short bf16x8;
typedef __attribute__((ext_vector_type(4))) float f32x4;

__device__ __forceinline__ u16 f2bf(float f) {
  unsigned u = __float_as_uint(f);
  u += 0x7FFFu + ((u >> 16) & 1u);
  return (u16)(u >> 16);
}
__device__ __forceinline__ float bf2f(u16 u) {
  return __uint_as_float(((unsigned)u) << 16);
}

#if __has_builtin(__builtin_amdgcn_exp2f)
#define EXP2F(x) __builtin_amdgcn_exp2f(x)
#else
#define EXP2F(x) exp2f(x)
#endif

#define MFMA(a, b, c) __builtin_amdgcn_mfma_f32_16x16x32_bf16(a, b, c, 0, 0, 0)

// exp(x*wgt/8) = exp2(x*wgt*log2(e)/8)
#define EXPC 0.18033688011112043f

// ---------------- K0: fp32 -> bf16 convert + fused mask/weight slice (j==7) -----------
__global__ __launch_bounds__(256) void k_convert(
    const float* __restrict__ s0, const float* __restrict__ s1, const float* __restrict__ s2,
    const float* __restrict__ s3, const float* __restrict__ s4, const float* __restrict__ s5,
    const float* __restrict__ s6,
    u16* __restrict__ d0, u16* __restrict__ d1, u16* __restrict__ d2, u16* __restrict__ d3,
    u16* __restrict__ d4, u16* __restrict__ d5, u16* __restrict__ d6,
    const float* __restrict__ attw, const int* __restrict__ amask, u16* __restrict__ fw) {
  const int j = blockIdx.y;
  if (j == 7) {  // fw[b,q,k] = amask ? NaN : bf16(attw); 8.39M elems, 8 per thread
    const int i = (blockIdx.x * 256 + threadIdx.x) * 8;
#pragma unroll
    for (int hh = 0; hh < 2; hh++) {
      const float4 w = *(const float4*)(attw + i + 4 * hh);
      const int4 m = *(const int4*)(amask + i + 4 * hh);
      ushort4 o;
      o.x = m.x ? 0x7FC0 : f2bf(w.x);
      o.y = m.y ? 0x7FC0 : f2bf(w.y);
      o.z = m.z ? 0x7FC0 : f2bf(w.z);
      o.w = m.w ? 0x7FC0 : f2bf(w.w);
      *(ushort4*)(fw + i + 4 * hh) = o;
    }
    return;
  }
  const int n = (j < 3) ? (4 * 1024 * 1024) : (1024 * 1024);
  const int i = (blockIdx.x * 256 + threadIdx.x) * 4;
  if (i >= n) return;
  const float* s = (j == 0) ? s0 : (j == 1) ? s1 : (j == 2) ? s2 : (j == 3) ? s3
                  : (j == 4) ? s4 : (j == 5) ? s5 : s6;
  u16* d = (j == 0) ? d0 : (j == 1) ? d1 : (j == 2) ? d2 : (j == 3) ? d3
          : (j == 4) ? d4 : (j == 5) ? d5 : d6;
  const float4 f = *(const float4*)(s + i);
  ushort4 o;
  o.x = f2bf(f.x); o.y = f2bf(f.y); o.z = f2bf(f.z); o.w = f2bf(f.w);
  *(ushort4*)(d + i) = o;
}

// ---------------- shared 128x128 bf16 GEMM core: Y = A[M,1024] * W[N,1024]^T -----------
__device__ __forceinline__ void gemm_core(
    const u16* __restrict__ A, const u16* __restrict__ Wm,
    int tm, int tn, u16* As, u16* Bs, f32x4 acc[4][4]) {
  const int tid = threadIdx.x;
  const int lane = tid & 63;
  const int wid = tid >> 6;
  const int wm = (wid >> 1) * 64, wn = (wid & 1) * 64;
  const int cc = lane & 15, gg = lane >> 4;
  const int srow = tid >> 2, scol = 8 * (tid & 3);
  const size_t ra0 = (size_t)(tm + srow) * DM + scol;
  const size_t ra1 = (size_t)(tm + 64 + srow) * DM + scol;
  const size_t rb0 = (size_t)(tn + srow) * DM + scol;
  const size_t rb1 = (size_t)(tn + 64 + srow) * DM + scol;
  const f32x4 Z4 = {0.f, 0.f, 0.f, 0.f};
#pragma unroll
  for (int i = 0; i < 4; i++)
#pragma unroll
    for (int j = 0; j < 4; j++) acc[i][j] = Z4;

  *(bf16x8*)&As[tid * 8]        = *(const bf16x8*)(A + ra0);
  *(bf16x8*)&As[2048 + tid * 8] = *(const bf16x8*)(A + ra1);
  *(bf16x8*)&Bs[tid * 8]        = *(const bf16x8*)(Wm + rb0);
  *(bf16x8*)&Bs[2048 + tid * 8] = *(const bf16x8*)(Wm + rb1);

  int buf = 0;
  for (int kk = 0; kk < DM; kk += 32) {
    __syncthreads();
    const int o = buf * 4096;
    bf16x8 af[4], bv[4];
#pragma unroll
    for (int i = 0; i < 4; i++) af[i] = *(const bf16x8*)&As[o + (wm + i * 16 + cc) * 32 + 8 * gg];
#pragma unroll
    for (int i = 0; i < 4; i++) bv[i] = *(const bf16x8*)&Bs[o + (wn + i * 16 + cc) * 32 + 8 * gg];
    if (kk + 32 < DM) {
      const int p = (buf ^ 1) * 4096;
      *(bf16x8*)&As[p + tid * 8]        = *(const bf16x8*)(A + ra0 + kk + 32);
      *(bf16x8*)&As[p + 2048 + tid * 8] = *(const bf16x8*)(A + ra1 + kk + 32);
      *(bf16x8*)&Bs[p + tid * 8]        = *(const bf16x8*)(Wm + rb0 + kk + 32);
      *(bf16x8*)&Bs[p + 2048 + tid * 8] = *(const bf16x8*)(Wm + rb1 + kk + 32);
    }
#pragma unroll
    for (int mi = 0; mi < 4; mi++)
#pragma unroll
      for (int ni = 0; ni < 4; ni++) acc[mi][ni] = MFMA(af[mi], bv[ni], acc[mi][ni]);
    buf ^= 1;
  }
}

// ---------------- K1: QKV projections (z = 0/1/2 -> q/k/v), masked, head-split bf16 ----
__global__ __launch_bounds__(256) void k_proj(
    const u16* __restrict__ xq, const u16* __restrict__ xk, const u16* __restrict__ xv,
    const u16* __restrict__ wqb, const u16* __restrict__ wkb, const u16* __restrict__ wvb,
    const float* __restrict__ bq, const float* __restrict__ bk, const float* __restrict__ bv,
    const float* __restrict__ qmask, const float* __restrict__ kmask,
    u16* __restrict__ q_ws, u16* __restrict__ k_ws, u16* __restrict__ vT_ws) {
  __shared__ u16 As[2 * 4096];
  __shared__ u16 Bs[2 * 4096];
  const int z = blockIdx.z;
  const u16* A = (z == 0) ? xq : (z == 1) ? xk : xv;
  const u16* Wm = (z == 0) ? wqb : (z == 1) ? wkb : wvb;
  const float* bias = (z == 0) ? bq : (z == 1) ? bk : bv;
  const float* rmask = (z == 0) ? qmask : kmask;
  const int tm = blockIdx.x * 128, tn = blockIdx.y * 128;
  f32x4 acc[4][4];
  gemm_core(A, Wm, tm, tn, As, Bs, acc);

  const int lane = threadIdx.x & 63;
  const int wid = threadIdx.x >> 6;
  const int wm = (wid >> 1) * 64, wn = (wid & 1) * 64;
  const int cc = lane & 15, gg = lane >> 4;
  const int b = tm >> 11;
  const int tok0 = tm & 2047;
#pragma unroll
  for (int mi = 0; mi < 4; mi++) {
    const int rl = wm + mi * 16 + 4 * gg;
    float rm[4];
#pragma unroll
    for (int r = 0; r < 4; r++) rm[r] = rmask[b * NQ + tok0 + rl + r];
#pragma unroll
    for (int ni = 0; ni < 4; ni++) {
      const int col = tn + wn + ni * 16 + cc;
      const int h = col >> 6, d = col & 63;
      const float bs = bias[col];
      f32x4 a = acc[mi][ni];
      if (z <= 1) {
        u16* dst = ((z == 0) ? q_ws : k_ws) +
                   ((size_t)(b * NH + h) * NQ + tok0 + rl) * DK + d;
#pragma unroll
        for (int r = 0; r < 4; r++) dst[(size_t)r * DK] = f2bf((a[r] + bs) * rm[r]);
      } else {
        ushort4 pk;
        pk.x = f2bf((a[0] + bs) * rm[0]);
        pk.y = f2bf((a[1] + bs) * rm[1]);
        pk.z = f2bf((a[2] + bs) * rm[2]);
        pk.w = f2bf((a[3] + bs) * rm[3]);
        *(ushort4*)(vT_ws + ((size_t)(b * NH + h) * DK + d) * NK + tok0 + rl) = pk;
      }
    }
  }
}

// ---------------- K3: merged softmax-sum + att write + PV ----------------------------
// loop1: row sums over stride-128 K tiles; butterfly -> rinv (no l_ws, no extra kernel)
// loop2: recompute logits, write att fp32 (nt), PV via bf16 MFMA
__global__ __launch_bounds__(256) void k_attn(
    const u16* __restrict__ q_ws, const u16* __restrict__ k_ws, const u16* __restrict__ vT_ws,
    const u16* __restrict__ fw, float* __restrict__ att_out, u16* __restrict__ ctxb) {
  __shared__ u16 Ks[128][72];         // loop1: 128 K rows; loop2: K rows 0..63, V rows 64..127
  __shared__ u16 Ps[4][16][72];
  const int bh = blockIdx.y;
  const int b = bh >> 4, hh = bh & 15;
  const int qb = blockIdx.x * 64;
  const int tid = threadIdx.x, lane = tid & 63, wid = tid >> 6;
  const int cc = lane & 15, gg = lane >> 4;
  const int qr0 = qb + wid * 16;
  const u16* qp = q_ws + ((size_t)bh * NQ + qr0 + cc) * DK + 8 * gg;
  const bf16x8 aq0 = *(const bf16x8*)qp;
  const bf16x8 aq1 = *(const bf16x8*)(qp + 32);
  const u16* fwrow = fw + ((size_t)b * NQ + qr0 + cc) * NK;
  const f32x4 Z4 = {0.f, 0.f, 0.f, 0.f};
  const int sr = tid >> 3, sc = 8 * (tid & 7);

  // ---- loop1: denominators ----
  float sum = 0.f;
  for (int kc = 0; kc < NK; kc += 128) {
#pragma unroll
    for (int i = 0; i < 4; i++)
      *(bf16x8*)&Ks[i * 32 + sr][sc] =
          *(const bf16x8*)(k_ws + ((size_t)bh * NK + kc + i * 32 + sr) * DK + sc);
    __syncthreads();
#pragma unroll
    for (int n = 0; n < 8; n++) {
      const bf16x8 k0 = *(const bf16x8*)&Ks[n * 16 + cc][8 * gg];
      const bf16x8 k1 = *(const bf16x8*)&Ks[n * 16 + cc][32 + 8 * gg];
      f32x4 acc = Z4;
      acc = MFMA(k0, aq0, acc);
      acc = MFMA(k1, aq1, acc);
      const int k0i = kc + n * 16 + 4 * gg;
      const ushort4 fv = *(const ushort4*)(fwrow + k0i);
      const float e0 = EXP2F(acc[0] * bf2f(fv.x) * EXPC);
      const float e1 = EXP2F(acc[1] * bf2f(fv.y) * EXPC);
      const float e2 = EXP2F(acc[2] * bf2f(fv.z) * EXPC);
      const float e3 = EXP2F(acc[3] * bf2f(fv.w) * EXPC);
      sum += (e0 == e0) ? e0 : 0.f;   // NaN w (masked) -> contributes 0
      sum += (e1 == e1) ? e1 : 0.f;
      sum += (e2 == e2) ? e2 : 0.f;
      sum += (e3 == e3) ? e3 : 0.f;
    }
    __syncthreads();
  }
  sum += __shfl_xor(sum, 16);
  sum += __shfl_xor(sum, 32);         // butterfly: every lane now holds the full row sum
  const float rinv = (sum > 0.f) ? 1.0f / sum : 0.f;

  // ---- loop2: normalize, write att, PV ----
  f32x4 o[4];
#pragma unroll
  for (int i = 0; i < 4; i++) o[i] = Z4;
  float* attrow = att_out + (size_t)bh * NQ * NK + (size_t)(qr0 + cc) * NK;

  for (int kc = 0; kc < NK; kc += KC) {
#pragma unroll
    for (int i = 0; i < 2; i++) {
      *(bf16x8*)&Ks[i * 32 + sr][sc] =
          *(const bf16x8*)(k_ws + ((size_t)bh * NK + kc + i * 32 + sr) * DK + sc);
      *(bf16x8*)&Ks[64 + i * 32 + sr][sc] =                       // V tile aliases rows 64..127
          *(const bf16x8*)(vT_ws + ((size_t)bh * DK + i * 32 + sr) * NK + kc + sc);
    }
    __syncthreads();
    // QK^T swapped: p[q=cc][k=16n+4gg+r]
#pragma unroll
    for (int n = 0; n < 4; n++) {
      const bf16x8 k0 = *(const bf16x8*)&Ks[n * 16 + cc][8 * gg];
      const bf16x8 k1 = *(const bf16x8*)&Ks[n * 16 + cc][32 + 8 * gg];
      f32x4 acc = Z4;
      acc = MFMA(k0, aq0, acc);
      acc = MFMA(k1, aq1, acc);
      const int k0i = kc + n * 16 + 4 * gg;
      const ushort4 fv = *(const ushort4*)(fwrow + k0i);
      const float e0 = EXP2F(acc[0] * bf2f(fv.x) * EXPC);
      const float e1 = EXP2F(acc[1] * bf2f(fv.y) * EXPC);
      const float e2 = EXP2F(acc[2] * bf2f(fv.z) * EXPC);
      const float e3 = EXP2F(acc[3] * bf2f(fv.w) * EXPC);
      f32x4 pv;
      pv.x = (e0 == e0) ? e0 * rinv : 0.f;
      pv.y = (e1 == e1) ? e1 * rinv : 0.f;
      pv.z = (e2 == e2) ? e2 * rinv : 0.f;
      pv.w = (e3 == e3) ? e3 * rinv : 0.f;
      __builtin_nontemporal_store(pv, (f32x4*)(attrow + k0i));
      ushort4 pk;
      pk.x = f2bf(pv.x); pk.y = f2bf(pv.y); pk.z = f2bf(pv.z); pk.w = f2bf(pv.w);
      *(ushort4*)&Ps[wid][cc][n * 16 + 4 * gg] = pk;  // per-wave buffer: no barrier needed
    }
    // PV: O[16q x 64d] += P[16q x 64k] * V[64k x 64d]
    const bf16x8 pa0 = *(const bf16x8*)&Ps[wid][cc][8 * gg];
    const bf16x8 pa1 = *(const bf16x8*)&Ps[wid][cc][32 + 8 * gg];
#pragma unroll
    for (int nd = 0; nd < 4; nd++) {
      const bf16x8 vb0 = *(const bf16x8*)&Ks[64 + nd * 16 + cc][8 * gg];
      const bf16x8 vb1 = *(const bf16x8*)&Ks[64 + nd * 16 + cc][32 + 8 * gg];
      o[nd] = MFMA(pa0, vb0, o[nd]);
      o[nd] = MFMA(pa1, vb1, o[nd]);
    }
    __syncthreads();
  }
  // PV C-layout: O[q=4gg+r][d=nd*16+cc]
#pragma unroll
  for (int nd = 0; nd < 4; nd++)
#pragma unroll
    for (int r = 0; r < 4; r++)
      ctxb[((size_t)b * NQ + qr0 + 4 * gg + r) * DM + hh * 64 + nd * 16 + cc] = f2bf(o[nd][r]);
}

// ---------------- K4: out_final = ctx @ Wo^T + bo (fp32 out) --------------------------
__global__ __launch_bounds__(256) void k_oproj(
    const u16* __restrict__ ctxb, const u16* __restrict__ wob,
    const float* __restrict__ bo, float* __restrict__ outp) {
  __shared__ u16 As[2 * 4096];
  __shared__ u16 Bs[2 * 4096];
  const int tm = blockIdx.x * 128, tn = blockIdx.y * 128;
  f32x4 acc[4][4];
  gemm_core(ctxb, wob, tm, tn, As, Bs, acc);
  const int lane = threadIdx.x & 63;
  const int wid = threadIdx.x >> 6;
  const int wm = (wid >> 1) * 64, wn = (wid & 1) * 64;
  const int cc = lane & 15, gg = lane >> 4;
#pragma unroll
  for (int mi = 0; mi < 4; mi++) {
    const int rl = tm + wm + mi * 16 + 4 * gg;
#pragma unroll
    for (int ni = 0; ni < 4; ni++) {
      const int col = tn + wn + ni * 16 + cc;
      const float bs = bo[col];
      f32x4 a = acc[mi][ni];
#pragma unroll
      for (int r = 0; r < 4; r++) outp[(size_t)(rl + r) * DM + col] = a[r] + bs;
    }
  }
}

extern "C" void kernel_launch(void* const* d_in, const int* in_sizes, int n_in,
                              void* d_out, int out_size, void* d_ws, size_t ws_size,
                              hipStream_t stream) {
  (void)in_sizes; (void)n_in; (void)out_size; (void)ws_size;
  const float* queries = (const float*)d_in[0];
  const float* keys    = (const float*)d_in[1];
  const float* values  = (const float*)d_in[2];
  const float* qmask   = (const float*)d_in[3];
  const float* kmask   = (const float*)d_in[4];
  const int*   amask   = (const int*)d_in[5];   // bool -> int32 on device
  const float* attw    = (const float*)d_in[6];
  const float* Wq = (const float*)d_in[7];
  const float* Wk = (const float*)d_in[8];
  const float* Wv = (const float*)d_in[9];
  const float* Wo = (const float*)d_in[10];
  const float* bq = (const float*)d_in[11];
  const float* bk = (const float*)d_in[12];
  const float* bv = (const float*)d_in[13];
  const float* bo = (const float*)d_in[14];

  float* outf = (float*)d_out;
  float* att_out = outf + (size_t)4194304;

  // persistent scratch in d_ws: 50.25 MiB
  char* p = (char*)d_ws;
  u16* q_ws  = (u16*)p; p += (size_t)4194304 * 2;
  u16* k_ws  = (u16*)p; p += (size_t)4194304 * 2;
  u16* vT_ws = (u16*)p; p += (size_t)4194304 * 2;
  u16* ctxb  = (u16*)p; p += (size_t)4194304 * 2;
  u16* wob   = (u16*)p; p += (size_t)1048576 * 2;  // read by k_oproj AFTER k_attn -> persist
  u16* fw    = (u16*)p; p += (size_t)8388608 * 2;  // fused mask+weight, read by k_attn

  // transient bf16 copies (all consumed by k_proj, BEFORE k_attn clobbers att region)
  char* t = (char*)att_out;
  u16* xq  = (u16*)t; t += (size_t)4194304 * 2;
  u16* xk  = (u16*)t; t += (size_t)4194304 * 2;
  u16* xv  = (u16*)t; t += (size_t)4194304 * 2;
  u16* wqb = (u16*)t; t += (size_t)1048576 * 2;
  u16* wkb = (u16*)t; t += (size_t)1048576 * 2;
  u16* wvb = (u16*)t; t += (size_t)1048576 * 2;

  k_convert<<<dim3(4096, 8, 1), 256, 0, stream>>>(queries, keys, values, Wq, Wk, Wv, Wo,
                                                  xq, xk, xv, wqb, wkb, wvb, wob,
                                                  attw, amask, fw);
  k_proj<<<dim3(32, 8, 3), 256, 0, stream>>>(xq, xk, xv, wqb, wkb, wvb, bq, bk, bv,
                                             qmask, kmask, q_ws, k_ws, vT_ws);
  k_attn<<<dim3(32, 32, 1), 256, 0, stream>>>(q_ws, k_ws, vT_ws, fw, att_out, ctxb);
  k_oproj<<<dim3(32, 8, 1), 256, 0, stream>>>(ctxb, wob, bo, outf);
}